// Round 10
// baseline (452.795 us; speedup 1.0000x reference)
//
#include <hip/hip_runtime.h>
#include <math.h>

// Problem constants (match reference)
#define B 8
#define N 500
#define K 16
#define D 32
#define C 16
#define T_IN 12
#define T_OUT 12
#define NNODE (B * N)

// Quad-lane DPP permute (VALU pipe, no LDS). CTRL: quad_perm selector byte.
// Broadcast lane j of each aligned quad: CTRL = j * 0x55.
// XOR1 = 0xB1 ([1,0,3,2]), XOR2 = 0x4E ([2,3,0,1]).
template <int CTRL>
__device__ __forceinline__ float qperm(float v) {
    return __int_as_float(__builtin_amdgcn_update_dpp(
        0, __float_as_int(v), CTRL, 0xF, 0xF, true));
}

// Single fused kernel (round-8 structure, register-pressure fixed).
// Block = 256 threads = 4 waves; wave w owns node blockIdx.x*4 + w.
// Lane l: s = l&3 (dims s*8..s*8+7 / classes s*4..s*4+3), g = l>>2 (neighbor).
// Each lane computes k (own node) and q (neighbor) for its 8 dims in the
// bit-exact order of all passing rounds (bias + e-ascending f32 accum).
// Weight streaming is chunked (4 e's per chunk) with compiler barriers so
// at most 16 float4 loads are in flight -> VGPR <= 128 (launch_bounds 256,4
// = 4 blocks/CU = 16 waves/CU).
__global__ __launch_bounds__(256, 4) void embed_gcn_one(
    const float* __restrict__ features,   // NNODE*D
    const float* __restrict__ input_seq,  // NNODE*T_IN
    const float* __restrict__ Wk,         // D*D
    const float* __restrict__ bk,         // D
    const float* __restrict__ Wq,         // D*D
    const float* __restrict__ bq,         // D
    const float* __restrict__ Wc,         // D*C
    const float* __restrict__ bc,         // C
    const float* __restrict__ Wcls,       // C*T_IN*T_OUT
    const int*   __restrict__ adj,        // NNODE*K
    float* __restrict__ out)              // NNODE*C*T_OUT
{
    const int tid  = threadIdx.x;
    const int w    = tid >> 6;
    const int l    = tid & 63;
    const int s    = l & 3;
    const int g    = l >> 2;
    const int node = blockIdx.x * 4 + w;
    const int b    = node / N;

    __shared__ __align__(16) float s_xT[4][T_IN][16];  // [wave][t][neighbor]
    __shared__ __align__(16) int   s_id[4][16];

    // ---- Independent loads first (latency overlap) ----
    const int j  = adj[(size_t)node * K + g];
    const int jn = b * N + j;
    // own features dims s*8..s*8+7 (same addr for all g -> L1 broadcast)
    const float4 fn0 = *(const float4*)&features[(size_t)node * D + s * 8];
    const float4 fn1 = *(const float4*)&features[(size_t)node * D + s * 8 + 4];
    // neighbor features (gather)
    const float4 fj0 = *(const float4*)&features[(size_t)jn * D + s * 8];
    const float4 fj1 = *(const float4*)&features[(size_t)jn * D + s * 8 + 4];
    if (s < 3) {
        const float4 x4 = *(const float4*)&input_seq[(size_t)jn * T_IN + s * 4];
        s_xT[w][s * 4 + 0][g] = x4.x;
        s_xT[w][s * 4 + 1][g] = x4.y;
        s_xT[w][s * 4 + 2][g] = x4.z;
        s_xT[w][s * 4 + 3][g] = x4.w;
    }

    // ---- k (own) and q (neighbor) for dims s*8..s*8+7 ----
    // bias first, e ascending: bit-identical to the kq table of rounds 1-6.
    float kacc[8], qacc[8];
    const float fnv[8] = { fn0.x, fn0.y, fn0.z, fn0.w,
                           fn1.x, fn1.y, fn1.z, fn1.w };
    const float fjv[8] = { fj0.x, fj0.y, fj0.z, fj0.w,
                           fj1.x, fj1.y, fj1.z, fj1.w };
    {
        const float4 bk0 = *(const float4*)&bk[s * 8];
        const float4 bk1 = *(const float4*)&bk[s * 8 + 4];
        const float4 bq0 = *(const float4*)&bq[s * 8];
        const float4 bq1 = *(const float4*)&bq[s * 8 + 4];
        kacc[0] = bk0.x; kacc[1] = bk0.y; kacc[2] = bk0.z; kacc[3] = bk0.w;
        kacc[4] = bk1.x; kacc[5] = bk1.y; kacc[6] = bk1.z; kacc[7] = bk1.w;
        qacc[0] = bq0.x; qacc[1] = bq0.y; qacc[2] = bq0.z; qacc[3] = bq0.w;
        qacc[4] = bq1.x; qacc[5] = bq1.y; qacc[6] = bq1.z; qacc[7] = bq1.w;
    }

    // One e-step: e = SQ*8 + I (I is a macro literal -> compile-time index).
#define KQE(CTRL, SQ, I) { \
    const int e = (SQ) * 8 + (I); \
    const float fne = qperm<CTRL>(fnv[I]); \
    const float fje = qperm<CTRL>(fjv[I]); \
    const float4 wk0 = *(const float4*)&Wk[e * D + s * 8]; \
    const float4 wk1 = *(const float4*)&Wk[e * D + s * 8 + 4]; \
    const float4 wq0 = *(const float4*)&Wq[e * D + s * 8]; \
    const float4 wq1 = *(const float4*)&Wq[e * D + s * 8 + 4]; \
    kacc[0] += fne * wk0.x;  kacc[1] += fne * wk0.y; \
    kacc[2] += fne * wk0.z;  kacc[3] += fne * wk0.w; \
    kacc[4] += fne * wk1.x;  kacc[5] += fne * wk1.y; \
    kacc[6] += fne * wk1.z;  kacc[7] += fne * wk1.w; \
    qacc[0] += fje * wq0.x;  qacc[1] += fje * wq0.y; \
    qacc[2] += fje * wq0.z;  qacc[3] += fje * wq0.w; \
    qacc[4] += fje * wq1.x;  qacc[5] += fje * wq1.y; \
    qacc[6] += fje * wq1.z;  qacc[7] += fje * wq1.w; }
    // Chunk boundary: compiler barrier stops load hoisting across chunks,
    // capping in-flight weight loads at 16 float4 (~64 VGPR).
#define KQ_FENCE asm volatile("" ::: "memory");

    KQE(0x00, 0, 0) KQE(0x00, 0, 1) KQE(0x00, 0, 2) KQE(0x00, 0, 3) KQ_FENCE
    KQE(0x00, 0, 4) KQE(0x00, 0, 5) KQE(0x00, 0, 6) KQE(0x00, 0, 7) KQ_FENCE
    KQE(0x55, 1, 0) KQE(0x55, 1, 1) KQE(0x55, 1, 2) KQE(0x55, 1, 3) KQ_FENCE
    KQE(0x55, 1, 4) KQE(0x55, 1, 5) KQE(0x55, 1, 6) KQE(0x55, 1, 7) KQ_FENCE
    KQE(0xAA, 2, 0) KQE(0xAA, 2, 1) KQE(0xAA, 2, 2) KQE(0xAA, 2, 3) KQ_FENCE
    KQE(0xAA, 2, 4) KQE(0xAA, 2, 5) KQE(0xAA, 2, 6) KQE(0xAA, 2, 7) KQ_FENCE
    KQE(0xFF, 3, 0) KQE(0xFF, 3, 1) KQE(0xFF, 3, 2) KQE(0xFF, 3, 3) KQ_FENCE
    KQE(0xFF, 3, 4) KQE(0xFF, 3, 5) KQE(0xFF, 3, 6) KQE(0xFF, 3, 7)
#undef KQE
#undef KQ_FENCE

    // ---- t = tanh(k + q), dims s*8..s*8+7 ----
    const float t0 = tanhf(kacc[0] + qacc[0]), t1 = tanhf(kacc[1] + qacc[1]);
    const float t2 = tanhf(kacc[2] + qacc[2]), t3 = tanhf(kacc[3] + qacc[3]);
    const float t4 = tanhf(kacc[4] + qacc[4]), t5 = tanhf(kacc[5] + qacc[5]);
    const float t6 = tanhf(kacc[6] + qacc[6]), t7 = tanhf(kacc[7] + qacc[7]);

    // ---- Quad broadcast: tc<j>[i] = t[8j+i] in EVERY lane (absolute order) ----
    float tc0[8], tc1[8], tc2[8], tc3[8];
#define BC(dst, CTRL) \
    dst[0] = qperm<CTRL>(t0); dst[1] = qperm<CTRL>(t1); \
    dst[2] = qperm<CTRL>(t2); dst[3] = qperm<CTRL>(t3); \
    dst[4] = qperm<CTRL>(t4); dst[5] = qperm<CTRL>(t5); \
    dst[6] = qperm<CTRL>(t6); dst[7] = qperm<CTRL>(t7);
    BC(tc0, 0x00)  BC(tc1, 0x55)  BC(tc2, 0xAA)  BC(tc3, 0xFF)
#undef BC

    // ---- Scores for classes s*4..s*4+3, d ascending (bit-frozen) ----
    {
        const float4 bc4 = *(const float4*)&bc[s * 4];
        float a0 = bc4.x, a1 = bc4.y, a2 = bc4.z, a3 = bc4.w;
        const float* __restrict__ wcp = Wc + s * 4;
        #pragma unroll
        for (int i = 0; i < 8; ++i) {
            const float4 w4 = *(const float4*)&wcp[(i) * C];
            a0 += tc0[i] * w4.x; a1 += tc0[i] * w4.y; a2 += tc0[i] * w4.z; a3 += tc0[i] * w4.w;
        }
        #pragma unroll
        for (int i = 0; i < 8; ++i) {
            const float4 w4 = *(const float4*)&wcp[(8 + i) * C];
            a0 += tc1[i] * w4.x; a1 += tc1[i] * w4.y; a2 += tc1[i] * w4.z; a3 += tc1[i] * w4.w;
        }
        #pragma unroll
        for (int i = 0; i < 8; ++i) {
            const float4 w4 = *(const float4*)&wcp[(16 + i) * C];
            a0 += tc2[i] * w4.x; a1 += tc2[i] * w4.y; a2 += tc2[i] * w4.z; a3 += tc2[i] * w4.w;
        }
        #pragma unroll
        for (int i = 0; i < 8; ++i) {
            const float4 w4 = *(const float4*)&wcp[(24 + i) * C];
            a0 += tc3[i] * w4.x; a1 += tc3[i] * w4.y; a2 += tc3[i] * w4.z; a3 += tc3[i] * w4.w;
        }

        // softmax-replicated argmax (identical to passing rounds)
        float m = fmaxf(fmaxf(a0, a1), fmaxf(a2, a3));
        m = fmaxf(m, __shfl_xor(m, 1, 4));
        m = fmaxf(m, __shfl_xor(m, 2, 4));
        const float e0 = expf(a0 - m), e1 = expf(a1 - m);
        const float e2 = expf(a2 - m), e3 = expf(a3 - m);
        float sum = e0 + e1 + e2 + e3;
        sum += __shfl_xor(sum, 1, 4);
        sum += __shfl_xor(sum, 2, 4);
        const float p0 = e0 / sum, p1 = e1 / sum, p2 = e2 / sum, p3 = e3 / sum;

        float bp = p0; int bi = s * 4;
        if (p1 > bp) { bp = p1; bi = s * 4 + 1; }
        if (p2 > bp) { bp = p2; bi = s * 4 + 2; }
        if (p3 > bp) { bp = p3; bi = s * 4 + 3; }
        #pragma unroll
        for (int off = 1; off <= 2; off <<= 1) {
            const float op = __shfl_xor(bp, off, 4);
            const int   oi = __shfl_xor(bi, off, 4);
            if (op > bp || (op == bp && oi < bi)) { bp = op; bi = oi; }
        }
        if (s == 0) s_id[w][g] = bi;
    }

    // ---- Masked mean. Lane owns (cc = l>>2, t-triple tq = l&3) ----
    const int cc = l >> 2;
    const int tq = l & 3;
    const int tbase = tq * 3;

    const int4 i0 = *(const int4*)&s_id[w][0];
    const int4 i1 = *(const int4*)&s_id[w][4];
    const int4 i2 = *(const int4*)&s_id[w][8];
    const int4 i3 = *(const int4*)&s_id[w][12];
    float msk[16]; int cnt = 0;
    {
        const int idv[16] = { i0.x, i0.y, i0.z, i0.w,  i1.x, i1.y, i1.z, i1.w,
                              i2.x, i2.y, i2.z, i2.w,  i3.x, i3.y, i3.z, i3.w };
        #pragma unroll
        for (int kk = 0; kk < 16; ++kk) {
            const bool h = (idv[kk] == cc);
            msk[kk] = h ? 1.f : 0.f;
            cnt += h;
        }
    }
    const float fcnt = (cnt == 0) ? 1.f : (float)cnt;

    float av0, av1, av2;
#define CELL(avx, T) { \
    const float4 xa = *(const float4*)&s_xT[w][T][0]; \
    const float4 xb = *(const float4*)&s_xT[w][T][4]; \
    const float4 xc = *(const float4*)&s_xT[w][T][8]; \
    const float4 xd = *(const float4*)&s_xT[w][T][12]; \
    float sm = 0.f; \
    sm += msk[0]*xa.x;  sm += msk[1]*xa.y;  sm += msk[2]*xa.z;  sm += msk[3]*xa.w; \
    sm += msk[4]*xb.x;  sm += msk[5]*xb.y;  sm += msk[6]*xb.z;  sm += msk[7]*xb.w; \
    sm += msk[8]*xc.x;  sm += msk[9]*xc.y;  sm += msk[10]*xc.z; sm += msk[11]*xc.w; \
    sm += msk[12]*xd.x; sm += msk[13]*xd.y; sm += msk[14]*xd.z; sm += msk[15]*xd.w; \
    avx = sm / fcnt; }
    CELL(av0, tbase)  CELL(av1, tbase + 1)  CELL(av2, tbase + 2)
#undef CELL

    // ---- out(cc,o) = tanh(sum_t avg_t * Wcls[cc][t][o]) ----
    const float* __restrict__ wcl = Wcls + ((size_t)cc * T_IN + tbase) * T_OUT;
    float p[12];
    {
        const float4 wA0 = *(const float4*)&wcl[0];
        const float4 wA1 = *(const float4*)&wcl[4];
        const float4 wA2 = *(const float4*)&wcl[8];
        p[0] = av0 * wA0.x;  p[1] = av0 * wA0.y;  p[2]  = av0 * wA0.z;  p[3]  = av0 * wA0.w;
        p[4] = av0 * wA1.x;  p[5] = av0 * wA1.y;  p[6]  = av0 * wA1.z;  p[7]  = av0 * wA1.w;
        p[8] = av0 * wA2.x;  p[9] = av0 * wA2.y;  p[10] = av0 * wA2.z;  p[11] = av0 * wA2.w;
        const float4 wB0 = *(const float4*)&wcl[12];
        const float4 wB1 = *(const float4*)&wcl[16];
        const float4 wB2 = *(const float4*)&wcl[20];
        p[0] += av1 * wB0.x;  p[1] += av1 * wB0.y;  p[2]  += av1 * wB0.z;  p[3]  += av1 * wB0.w;
        p[4] += av1 * wB1.x;  p[5] += av1 * wB1.y;  p[6]  += av1 * wB1.z;  p[7]  += av1 * wB1.w;
        p[8] += av1 * wB2.x;  p[9] += av1 * wB2.y;  p[10] += av1 * wB2.z;  p[11] += av1 * wB2.w;
        const float4 wC0 = *(const float4*)&wcl[24];
        const float4 wC1 = *(const float4*)&wcl[28];
        const float4 wC2 = *(const float4*)&wcl[32];
        p[0] += av2 * wC0.x;  p[1] += av2 * wC0.y;  p[2]  += av2 * wC0.z;  p[3]  += av2 * wC0.w;
        p[4] += av2 * wC1.x;  p[5] += av2 * wC1.y;  p[6]  += av2 * wC1.z;  p[7]  += av2 * wC1.w;
        p[8] += av2 * wC2.x;  p[9] += av2 * wC2.y;  p[10] += av2 * wC2.z;  p[11] += av2 * wC2.w;
    }
    #pragma unroll
    for (int o = 0; o < 12; ++o) {
        p[o] += qperm<0xB1>(p[o]);   // + partner tq^1
        p[o] += qperm<0x4E>(p[o]);   // + pair tq^2  -> full sum over t
    }
    #pragma unroll
    for (int i = 0; i < 3; ++i) {
        const float va = (tq & 1) ? p[3 + i] : p[i];
        const float vb = (tq & 1) ? p[9 + i] : p[6 + i];
        const float v  = (tq & 2) ? vb : va;
        out[(size_t)node * (C * T_OUT) + cc * T_OUT + tbase + i] = tanhf(v);
    }
}

extern "C" void kernel_launch(void* const* d_in, const int* in_sizes, int n_in,
                              void* d_out, int out_size, void* d_ws, size_t ws_size,
                              hipStream_t stream) {
    const float* features  = (const float*)d_in[0];
    const float* input_seq = (const float*)d_in[1];
    const float* Wk        = (const float*)d_in[2];
    const float* bk        = (const float*)d_in[3];
    const float* Wq        = (const float*)d_in[4];
    const float* bq        = (const float*)d_in[5];
    const float* Wc        = (const float*)d_in[6];
    const float* bc        = (const float*)d_in[7];
    const float* Wcls      = (const float*)d_in[8];
    const int*   adj       = (const int*)d_in[9];
    float*       out       = (float*)d_out;

    embed_gcn_one<<<NNODE / 4, 256, 0, stream>>>(
        features, input_seq, Wk, bk, Wq, bq, Wc, bc, Wcls, adj, out);
}

// Round 11
// 134.037 us; speedup vs baseline: 3.3781x; 3.3781x over previous
//
#include <hip/hip_runtime.h>
#include <math.h>

// Problem constants (match reference)
#define B 8
#define N 500
#define K 16
#define D 32
#define C 16
#define T_IN 12
#define T_OUT 12
#define NNODE (B * N)

// Quad-lane DPP permute (VALU pipe, no LDS). CTRL: quad_perm selector byte.
// Broadcast lane j of each aligned quad: CTRL = j * 0x55.
// XOR1 = 0xB1 ([1,0,3,2]), XOR2 = 0x4E ([2,3,0,1]).
template <int CTRL>
__device__ __forceinline__ float qperm(float v) {
    return __int_as_float(__builtin_amdgcn_update_dpp(
        0, __float_as_int(v), CTRL, 0xF, 0xF, true));
}

// Single fused kernel. Block = 256 threads = 4 waves; wave w owns node
// blockIdx.x*4 + w. Lane l: s = l&3 (dims s*8..+7 / classes s*4..+3),
// g = l>>2 (neighbor slot). Zero __syncthreads (all LDS traffic is
// wave-local; the in-order per-wave DS pipe orders write->read).
//
// k: computed ONCE per wave (all 64 lanes uniformly compute d = l&31;
//    lanes 0..31 store to s_k) -- bias + e-ascending, bit-identical to the
//    two-kernel rounds' kq table.
// q: per lane for (neighbor g, dims s*8..+7) -- no redundancy; neighbor
//    features quad-broadcast via DPP; Wq streamed as L1-broadcast b128.
// Then round-6 consumer verbatim (DPP t-broadcast, bit-frozen scores/
// softmax/argmax, masked mean, Wcls matmul).
//
// __launch_bounds__(256,4): <=128 VGPR target, 4 blocks/CU, 16 waves/CU.
// NO scheduling fences (round-10 lesson: fences + cap => scratch spill).
__global__ __launch_bounds__(256, 4) void embed_gcn_one(
    const float* __restrict__ features,   // NNODE*D
    const float* __restrict__ input_seq,  // NNODE*T_IN
    const float* __restrict__ Wk,         // D*D
    const float* __restrict__ bk,         // D
    const float* __restrict__ Wq,         // D*D
    const float* __restrict__ bq,         // D
    const float* __restrict__ Wc,         // D*C
    const float* __restrict__ bc,         // C
    const float* __restrict__ Wcls,       // C*T_IN*T_OUT
    const int*   __restrict__ adj,        // NNODE*K
    float* __restrict__ out)              // NNODE*C*T_OUT
{
    const int tid  = threadIdx.x;
    const int w    = tid >> 6;
    const int l    = tid & 63;
    const int s    = l & 3;
    const int g    = l >> 2;
    const int node = blockIdx.x * 4 + w;
    const int b    = node / N;

    __shared__ float s_f[4][D];                        // own features row
    __shared__ __align__(16) float s_k[4][D];          // own k row
    __shared__ __align__(16) float s_xT[4][T_IN][16];  // [wave][t][neighbor]
    __shared__ __align__(16) int   s_id[4][16];

    // ---- Independent loads first (latency overlap) ----
    const int j  = adj[(size_t)node * K + g];
    const int jn = b * N + j;
    // neighbor features, dims s*8..s*8+7 (per-lane gather)
    const float4 fj0 = *(const float4*)&features[(size_t)jn * D + s * 8];
    const float4 fj1 = *(const float4*)&features[(size_t)jn * D + s * 8 + 4];
    // own features staged for the k pass (wave-local LDS)
    if (l < D) s_f[w][l] = features[(size_t)node * D + l];
    if (s < 3) {
        const float4 x4 = *(const float4*)&input_seq[(size_t)jn * T_IN + s * 4];
        s_xT[w][s * 4 + 0][g] = x4.x;
        s_xT[w][s * 4 + 1][g] = x4.y;
        s_xT[w][s * 4 + 2][g] = x4.z;
        s_xT[w][s * 4 + 3][g] = x4.w;
    }

    // ---- k pass: once per wave. All lanes uniform (d = l&31, lanes 32-63
    // duplicate lanes 0-31); predicated store by lanes 0..31.
    // bias first, e ascending -> bit-identical to rounds 1-6 k.
    {
        const int d = l & 31;
        float acc = bk[d];
        #pragma unroll
        for (int e = 0; e < D; ++e) acc += s_f[w][e] * Wk[e * D + d];
        if (l < D) s_k[w][l] = acc;
    }

    // ---- q pass: lane owns (neighbor g, dims s*8..s*8+7). bias first,
    // e ascending (4 static chunks x 8, DPP source rotates) -> bit-identical.
    float qacc[8];
    {
        const float4 bq0 = *(const float4*)&bq[s * 8];
        const float4 bq1 = *(const float4*)&bq[s * 8 + 4];
        qacc[0] = bq0.x; qacc[1] = bq0.y; qacc[2] = bq0.z; qacc[3] = bq0.w;
        qacc[4] = bq1.x; qacc[5] = bq1.y; qacc[6] = bq1.z; qacc[7] = bq1.w;
    }
    const float fjv[8] = { fj0.x, fj0.y, fj0.z, fj0.w,
                           fj1.x, fj1.y, fj1.z, fj1.w };
#define QCHUNK(CTRL, SQ) \
    _Pragma("unroll") \
    for (int i = 0; i < 8; ++i) { \
        const int e = (SQ) * 8 + i; \
        const float fje = qperm<CTRL>(fjv[i]); \
        const float4 wq0 = *(const float4*)&Wq[e * D + s * 8]; \
        const float4 wq1 = *(const float4*)&Wq[e * D + s * 8 + 4]; \
        qacc[0] += fje * wq0.x;  qacc[1] += fje * wq0.y; \
        qacc[2] += fje * wq0.z;  qacc[3] += fje * wq0.w; \
        qacc[4] += fje * wq1.x;  qacc[5] += fje * wq1.y; \
        qacc[6] += fje * wq1.z;  qacc[7] += fje * wq1.w; \
    }
    QCHUNK(0x00, 0)
    QCHUNK(0x55, 1)
    QCHUNK(0xAA, 2)
    QCHUNK(0xFF, 3)
#undef QCHUNK

    // ---- t = tanh(k + q), dims s*8..s*8+7 (k via LDS broadcast read) ----
    const float4 k0 = *(const float4*)&s_k[w][s * 8];
    const float4 k1 = *(const float4*)&s_k[w][s * 8 + 4];
    const float t0 = tanhf(k0.x + qacc[0]), t1 = tanhf(k0.y + qacc[1]);
    const float t2 = tanhf(k0.z + qacc[2]), t3 = tanhf(k0.w + qacc[3]);
    const float t4 = tanhf(k1.x + qacc[4]), t5 = tanhf(k1.y + qacc[5]);
    const float t6 = tanhf(k1.z + qacc[6]), t7 = tanhf(k1.w + qacc[7]);

    // ---- Quad broadcast: tc<j>[i] = t[8j+i] in EVERY lane (absolute order) ----
    float tc0[8], tc1[8], tc2[8], tc3[8];
#define BC(dst, CTRL) \
    dst[0] = qperm<CTRL>(t0); dst[1] = qperm<CTRL>(t1); \
    dst[2] = qperm<CTRL>(t2); dst[3] = qperm<CTRL>(t3); \
    dst[4] = qperm<CTRL>(t4); dst[5] = qperm<CTRL>(t5); \
    dst[6] = qperm<CTRL>(t6); dst[7] = qperm<CTRL>(t7);
    BC(tc0, 0x00)  BC(tc1, 0x55)  BC(tc2, 0xAA)  BC(tc3, 0xFF)
#undef BC

    // ---- Scores for classes s*4..s*4+3, d ascending (bit-frozen) ----
    {
        const float4 bc4 = *(const float4*)&bc[s * 4];
        float a0 = bc4.x, a1 = bc4.y, a2 = bc4.z, a3 = bc4.w;
        const float* __restrict__ wcp = Wc + s * 4;
        #pragma unroll
        for (int i = 0; i < 8; ++i) {
            const float4 w4 = *(const float4*)&wcp[(i) * C];
            a0 += tc0[i] * w4.x; a1 += tc0[i] * w4.y; a2 += tc0[i] * w4.z; a3 += tc0[i] * w4.w;
        }
        #pragma unroll
        for (int i = 0; i < 8; ++i) {
            const float4 w4 = *(const float4*)&wcp[(8 + i) * C];
            a0 += tc1[i] * w4.x; a1 += tc1[i] * w4.y; a2 += tc1[i] * w4.z; a3 += tc1[i] * w4.w;
        }
        #pragma unroll
        for (int i = 0; i < 8; ++i) {
            const float4 w4 = *(const float4*)&wcp[(16 + i) * C];
            a0 += tc2[i] * w4.x; a1 += tc2[i] * w4.y; a2 += tc2[i] * w4.z; a3 += tc2[i] * w4.w;
        }
        #pragma unroll
        for (int i = 0; i < 8; ++i) {
            const float4 w4 = *(const float4*)&wcp[(24 + i) * C];
            a0 += tc3[i] * w4.x; a1 += tc3[i] * w4.y; a2 += tc3[i] * w4.z; a3 += tc3[i] * w4.w;
        }

        // softmax-replicated argmax (identical to passing rounds)
        float m = fmaxf(fmaxf(a0, a1), fmaxf(a2, a3));
        m = fmaxf(m, __shfl_xor(m, 1, 4));
        m = fmaxf(m, __shfl_xor(m, 2, 4));
        const float e0 = expf(a0 - m), e1 = expf(a1 - m);
        const float e2 = expf(a2 - m), e3 = expf(a3 - m);
        float sum = e0 + e1 + e2 + e3;
        sum += __shfl_xor(sum, 1, 4);
        sum += __shfl_xor(sum, 2, 4);
        const float p0 = e0 / sum, p1 = e1 / sum, p2 = e2 / sum, p3 = e3 / sum;

        float bp = p0; int bi = s * 4;
        if (p1 > bp) { bp = p1; bi = s * 4 + 1; }
        if (p2 > bp) { bp = p2; bi = s * 4 + 2; }
        if (p3 > bp) { bp = p3; bi = s * 4 + 3; }
        #pragma unroll
        for (int off = 1; off <= 2; off <<= 1) {
            const float op = __shfl_xor(bp, off, 4);
            const int   oi = __shfl_xor(bi, off, 4);
            if (op > bp || (op == bp && oi < bi)) { bp = op; bi = oi; }
        }
        if (s == 0) s_id[w][g] = bi;
    }

    // ---- Masked mean. Lane owns (cc = l>>2, t-triple tq = l&3) ----
    const int cc = l >> 2;
    const int tq = l & 3;
    const int tbase = tq * 3;

    const int4 i0 = *(const int4*)&s_id[w][0];
    const int4 i1 = *(const int4*)&s_id[w][4];
    const int4 i2 = *(const int4*)&s_id[w][8];
    const int4 i3 = *(const int4*)&s_id[w][12];
    float msk[16]; int cnt = 0;
    {
        const int idv[16] = { i0.x, i0.y, i0.z, i0.w,  i1.x, i1.y, i1.z, i1.w,
                              i2.x, i2.y, i2.z, i2.w,  i3.x, i3.y, i3.z, i3.w };
        #pragma unroll
        for (int kk = 0; kk < 16; ++kk) {
            const bool h = (idv[kk] == cc);
            msk[kk] = h ? 1.f : 0.f;
            cnt += h;
        }
    }
    const float fcnt = (cnt == 0) ? 1.f : (float)cnt;

    float av0, av1, av2;
#define CELL(avx, T) { \
    const float4 xa = *(const float4*)&s_xT[w][T][0]; \
    const float4 xb = *(const float4*)&s_xT[w][T][4]; \
    const float4 xc = *(const float4*)&s_xT[w][T][8]; \
    const float4 xd = *(const float4*)&s_xT[w][T][12]; \
    float sm = 0.f; \
    sm += msk[0]*xa.x;  sm += msk[1]*xa.y;  sm += msk[2]*xa.z;  sm += msk[3]*xa.w; \
    sm += msk[4]*xb.x;  sm += msk[5]*xb.y;  sm += msk[6]*xb.z;  sm += msk[7]*xb.w; \
    sm += msk[8]*xc.x;  sm += msk[9]*xc.y;  sm += msk[10]*xc.z; sm += msk[11]*xc.w; \
    sm += msk[12]*xd.x; sm += msk[13]*xd.y; sm += msk[14]*xd.z; sm += msk[15]*xd.w; \
    avx = sm / fcnt; }
    CELL(av0, tbase)  CELL(av1, tbase + 1)  CELL(av2, tbase + 2)
#undef CELL

    // ---- out(cc,o) = tanh(sum_t avg_t * Wcls[cc][t][o]) ----
    const float* __restrict__ wcl = Wcls + ((size_t)cc * T_IN + tbase) * T_OUT;
    float p[12];
    {
        const float4 wA0 = *(const float4*)&wcl[0];
        const float4 wA1 = *(const float4*)&wcl[4];
        const float4 wA2 = *(const float4*)&wcl[8];
        p[0] = av0 * wA0.x;  p[1] = av0 * wA0.y;  p[2]  = av0 * wA0.z;  p[3]  = av0 * wA0.w;
        p[4] = av0 * wA1.x;  p[5] = av0 * wA1.y;  p[6]  = av0 * wA1.z;  p[7]  = av0 * wA1.w;
        p[8] = av0 * wA2.x;  p[9] = av0 * wA2.y;  p[10] = av0 * wA2.z;  p[11] = av0 * wA2.w;
        const float4 wB0 = *(const float4*)&wcl[12];
        const float4 wB1 = *(const float4*)&wcl[16];
        const float4 wB2 = *(const float4*)&wcl[20];
        p[0] += av1 * wB0.x;  p[1] += av1 * wB0.y;  p[2]  += av1 * wB0.z;  p[3]  += av1 * wB0.w;
        p[4] += av1 * wB1.x;  p[5] += av1 * wB1.y;  p[6]  += av1 * wB1.z;  p[7]  += av1 * wB1.w;
        p[8] += av1 * wB2.x;  p[9] += av1 * wB2.y;  p[10] += av1 * wB2.z;  p[11] += av1 * wB2.w;
        const float4 wC0 = *(const float4*)&wcl[24];
        const float4 wC1 = *(const float4*)&wcl[28];
        const float4 wC2 = *(const float4*)&wcl[32];
        p[0] += av2 * wC0.x;  p[1] += av2 * wC0.y;  p[2]  += av2 * wC0.z;  p[3]  += av2 * wC0.w;
        p[4] += av2 * wC1.x;  p[5] += av2 * wC1.y;  p[6]  += av2 * wC1.z;  p[7]  += av2 * wC1.w;
        p[8] += av2 * wC2.x;  p[9] += av2 * wC2.y;  p[10] += av2 * wC2.z;  p[11] += av2 * wC2.w;
    }
    #pragma unroll
    for (int o = 0; o < 12; ++o) {
        p[o] += qperm<0xB1>(p[o]);   // + partner tq^1
        p[o] += qperm<0x4E>(p[o]);   // + pair tq^2  -> full sum over t
    }
    #pragma unroll
    for (int i = 0; i < 3; ++i) {
        const float va = (tq & 1) ? p[3 + i] : p[i];
        const float vb = (tq & 1) ? p[9 + i] : p[6 + i];
        const float v  = (tq & 2) ? vb : va;
        out[(size_t)node * (C * T_OUT) + cc * T_OUT + tbase + i] = tanhf(v);
    }
}

extern "C" void kernel_launch(void* const* d_in, const int* in_sizes, int n_in,
                              void* d_out, int out_size, void* d_ws, size_t ws_size,
                              hipStream_t stream) {
    const float* features  = (const float*)d_in[0];
    const float* input_seq = (const float*)d_in[1];
    const float* Wk        = (const float*)d_in[2];
    const float* bk        = (const float*)d_in[3];
    const float* Wq        = (const float*)d_in[4];
    const float* bq        = (const float*)d_in[5];
    const float* Wc        = (const float*)d_in[6];
    const float* bc        = (const float*)d_in[7];
    const float* Wcls      = (const float*)d_in[8];
    const int*   adj       = (const int*)d_in[9];
    float*       out       = (float*)d_out;

    embed_gcn_one<<<NNODE / 4, 256, 0, stream>>>(
        features, input_seq, Wk, bk, Wq, bq, Wc, bc, Wcls, adj, out);
}

// Round 12
// 32.941 us; speedup vs baseline: 13.7456x; 4.0690x over previous
//
#include <hip/hip_runtime.h>
#include <math.h>

// Problem constants (match reference)
#define B 8
#define N 500
#define K 16
#define D 32
#define C 16
#define T_IN 12
#define T_OUT 12
#define NNODE (B * N)

// Quad-lane DPP permute (VALU pipe, no LDS). CTRL: quad_perm selector byte.
// Broadcast lane j of each aligned quad: CTRL = j * 0x55.
// XOR1 = 0xB1 ([1,0,3,2]), XOR2 = 0x4E ([2,3,0,1]).
template <int CTRL>
__device__ __forceinline__ float qperm(float v) {
    return __int_as_float(__builtin_amdgcn_update_dpp(
        0, __float_as_int(v), CTRL, 0xF, 0xF, true));
}

// Single fused kernel. Block = 256 threads = 4 waves; wave w owns node
// blockIdx.x*4 + w. Lane l: s = l&3 (dims s*8..+7 / classes s*4..+3),
// g = l>>2 (neighbor slot). Zero __syncthreads (all LDS traffic is
// wave-local; the in-order per-wave DS pipe orders write->read).
//
// k: computed ONCE per wave (uniform d = l&31; lanes 0..31 store s_k),
//    bias + e-ascending -> bit-identical to the two-kernel rounds.
// q: per lane for (neighbor g, dims s*8..+7) -- no redundancy; neighbor
//    features quad-broadcast via DPP; Wq streamed as L1-broadcast b128.
// Then the round-6 consumer verbatim.
//
// __launch_bounds__(256) ONLY -- rounds 10/11 proved the min-occupancy
// arg (256,4) forces a 64-VGPR allocation that spills ~300+ MB to
// scratch. Round 8 proved the uncapped allocator does not spill.
__global__ __launch_bounds__(256) void embed_gcn_one(
    const float* __restrict__ features,   // NNODE*D
    const float* __restrict__ input_seq,  // NNODE*T_IN
    const float* __restrict__ Wk,         // D*D
    const float* __restrict__ bk,         // D
    const float* __restrict__ Wq,         // D*D
    const float* __restrict__ bq,         // D
    const float* __restrict__ Wc,         // D*C
    const float* __restrict__ bc,         // C
    const float* __restrict__ Wcls,       // C*T_IN*T_OUT
    const int*   __restrict__ adj,        // NNODE*K
    float* __restrict__ out)              // NNODE*C*T_OUT
{
    const int tid  = threadIdx.x;
    const int w    = tid >> 6;
    const int l    = tid & 63;
    const int s    = l & 3;
    const int g    = l >> 2;
    const int node = blockIdx.x * 4 + w;
    const int b    = node / N;

    __shared__ float s_f[4][D];                        // own features row
    __shared__ __align__(16) float s_k[4][D];          // own k row
    __shared__ __align__(16) float s_xT[4][T_IN][16];  // [wave][t][neighbor]
    __shared__ __align__(16) int   s_id[4][16];

    // ---- Independent loads first (latency overlap) ----
    const int j  = adj[(size_t)node * K + g];
    const int jn = b * N + j;
    // neighbor features, dims s*8..s*8+7 (per-lane gather)
    const float4 fj0 = *(const float4*)&features[(size_t)jn * D + s * 8];
    const float4 fj1 = *(const float4*)&features[(size_t)jn * D + s * 8 + 4];
    // own features staged for the k pass (wave-local LDS)
    if (l < D) s_f[w][l] = features[(size_t)node * D + l];
    if (s < 3) {
        const float4 x4 = *(const float4*)&input_seq[(size_t)jn * T_IN + s * 4];
        s_xT[w][s * 4 + 0][g] = x4.x;
        s_xT[w][s * 4 + 1][g] = x4.y;
        s_xT[w][s * 4 + 2][g] = x4.z;
        s_xT[w][s * 4 + 3][g] = x4.w;
    }

    // ---- k pass: once per wave. All lanes uniform (d = l&31); lanes
    // 0..31 store. bias first, e ascending -> bit-identical k.
    {
        const int d = l & 31;
        float acc = bk[d];
        #pragma unroll
        for (int e = 0; e < D; ++e) acc += s_f[w][e] * Wk[e * D + d];
        if (l < D) s_k[w][l] = acc;
    }

    // ---- q pass: lane owns (neighbor g, dims s*8..s*8+7). bias first,
    // e ascending (4 static chunks x 8, DPP source rotates) -> bit-identical.
    float qacc[8];
    {
        const float4 bq0 = *(const float4*)&bq[s * 8];
        const float4 bq1 = *(const float4*)&bq[s * 8 + 4];
        qacc[0] = bq0.x; qacc[1] = bq0.y; qacc[2] = bq0.z; qacc[3] = bq0.w;
        qacc[4] = bq1.x; qacc[5] = bq1.y; qacc[6] = bq1.z; qacc[7] = bq1.w;
    }
    const float fjv[8] = { fj0.x, fj0.y, fj0.z, fj0.w,
                           fj1.x, fj1.y, fj1.z, fj1.w };
#define QCHUNK(CTRL, SQ) \
    _Pragma("unroll") \
    for (int i = 0; i < 8; ++i) { \
        const int e = (SQ) * 8 + i; \
        const float fje = qperm<CTRL>(fjv[i]); \
        const float4 wq0 = *(const float4*)&Wq[e * D + s * 8]; \
        const float4 wq1 = *(const float4*)&Wq[e * D + s * 8 + 4]; \
        qacc[0] += fje * wq0.x;  qacc[1] += fje * wq0.y; \
        qacc[2] += fje * wq0.z;  qacc[3] += fje * wq0.w; \
        qacc[4] += fje * wq1.x;  qacc[5] += fje * wq1.y; \
        qacc[6] += fje * wq1.z;  qacc[7] += fje * wq1.w; \
    }
    QCHUNK(0x00, 0)
    QCHUNK(0x55, 1)
    QCHUNK(0xAA, 2)
    QCHUNK(0xFF, 3)
#undef QCHUNK

    // ---- t = tanh(k + q), dims s*8..s*8+7 (k via LDS broadcast read) ----
    const float4 k0 = *(const float4*)&s_k[w][s * 8];
    const float4 k1 = *(const float4*)&s_k[w][s * 8 + 4];
    const float t0 = tanhf(k0.x + qacc[0]), t1 = tanhf(k0.y + qacc[1]);
    const float t2 = tanhf(k0.z + qacc[2]), t3 = tanhf(k0.w + qacc[3]);
    const float t4 = tanhf(k1.x + qacc[4]), t5 = tanhf(k1.y + qacc[5]);
    const float t6 = tanhf(k1.z + qacc[6]), t7 = tanhf(k1.w + qacc[7]);

    // ---- Quad broadcast: tc<j>[i] = t[8j+i] in EVERY lane (absolute order) ----
    float tc0[8], tc1[8], tc2[8], tc3[8];
#define BC(dst, CTRL) \
    dst[0] = qperm<CTRL>(t0); dst[1] = qperm<CTRL>(t1); \
    dst[2] = qperm<CTRL>(t2); dst[3] = qperm<CTRL>(t3); \
    dst[4] = qperm<CTRL>(t4); dst[5] = qperm<CTRL>(t5); \
    dst[6] = qperm<CTRL>(t6); dst[7] = qperm<CTRL>(t7);
    BC(tc0, 0x00)  BC(tc1, 0x55)  BC(tc2, 0xAA)  BC(tc3, 0xFF)
#undef BC

    // ---- Scores for classes s*4..s*4+3, d ascending (bit-frozen) ----
    {
        const float4 bc4 = *(const float4*)&bc[s * 4];
        float a0 = bc4.x, a1 = bc4.y, a2 = bc4.z, a3 = bc4.w;
        const float* __restrict__ wcp = Wc + s * 4;
        #pragma unroll
        for (int i = 0; i < 8; ++i) {
            const float4 w4 = *(const float4*)&wcp[(i) * C];
            a0 += tc0[i] * w4.x; a1 += tc0[i] * w4.y; a2 += tc0[i] * w4.z; a3 += tc0[i] * w4.w;
        }
        #pragma unroll
        for (int i = 0; i < 8; ++i) {
            const float4 w4 = *(const float4*)&wcp[(8 + i) * C];
            a0 += tc1[i] * w4.x; a1 += tc1[i] * w4.y; a2 += tc1[i] * w4.z; a3 += tc1[i] * w4.w;
        }
        #pragma unroll
        for (int i = 0; i < 8; ++i) {
            const float4 w4 = *(const float4*)&wcp[(16 + i) * C];
            a0 += tc2[i] * w4.x; a1 += tc2[i] * w4.y; a2 += tc2[i] * w4.z; a3 += tc2[i] * w4.w;
        }
        #pragma unroll
        for (int i = 0; i < 8; ++i) {
            const float4 w4 = *(const float4*)&wcp[(24 + i) * C];
            a0 += tc3[i] * w4.x; a1 += tc3[i] * w4.y; a2 += tc3[i] * w4.z; a3 += tc3[i] * w4.w;
        }

        // softmax-replicated argmax (identical to passing rounds)
        float m = fmaxf(fmaxf(a0, a1), fmaxf(a2, a3));
        m = fmaxf(m, __shfl_xor(m, 1, 4));
        m = fmaxf(m, __shfl_xor(m, 2, 4));
        const float e0 = expf(a0 - m), e1 = expf(a1 - m);
        const float e2 = expf(a2 - m), e3 = expf(a3 - m);
        float sum = e0 + e1 + e2 + e3;
        sum += __shfl_xor(sum, 1, 4);
        sum += __shfl_xor(sum, 2, 4);
        const float p0 = e0 / sum, p1 = e1 / sum, p2 = e2 / sum, p3 = e3 / sum;

        float bp = p0; int bi = s * 4;
        if (p1 > bp) { bp = p1; bi = s * 4 + 1; }
        if (p2 > bp) { bp = p2; bi = s * 4 + 2; }
        if (p3 > bp) { bp = p3; bi = s * 4 + 3; }
        #pragma unroll
        for (int off = 1; off <= 2; off <<= 1) {
            const float op = __shfl_xor(bp, off, 4);
            const int   oi = __shfl_xor(bi, off, 4);
            if (op > bp || (op == bp && oi < bi)) { bp = op; bi = oi; }
        }
        if (s == 0) s_id[w][g] = bi;
    }

    // ---- Masked mean. Lane owns (cc = l>>2, t-triple tq = l&3) ----
    const int cc = l >> 2;
    const int tq = l & 3;
    const int tbase = tq * 3;

    const int4 i0 = *(const int4*)&s_id[w][0];
    const int4 i1 = *(const int4*)&s_id[w][4];
    const int4 i2 = *(const int4*)&s_id[w][8];
    const int4 i3 = *(const int4*)&s_id[w][12];
    float msk[16]; int cnt = 0;
    {
        const int idv[16] = { i0.x, i0.y, i0.z, i0.w,  i1.x, i1.y, i1.z, i1.w,
                              i2.x, i2.y, i2.z, i2.w,  i3.x, i3.y, i3.z, i3.w };
        #pragma unroll
        for (int kk = 0; kk < 16; ++kk) {
            const bool h = (idv[kk] == cc);
            msk[kk] = h ? 1.f : 0.f;
            cnt += h;
        }
    }
    const float fcnt = (cnt == 0) ? 1.f : (float)cnt;

    float av0, av1, av2;
#define CELL(avx, T) { \
    const float4 xa = *(const float4*)&s_xT[w][T][0]; \
    const float4 xb = *(const float4*)&s_xT[w][T][4]; \
    const float4 xc = *(const float4*)&s_xT[w][T][8]; \
    const float4 xd = *(const float4*)&s_xT[w][T][12]; \
    float sm = 0.f; \
    sm += msk[0]*xa.x;  sm += msk[1]*xa.y;  sm += msk[2]*xa.z;  sm += msk[3]*xa.w; \
    sm += msk[4]*xb.x;  sm += msk[5]*xb.y;  sm += msk[6]*xb.z;  sm += msk[7]*xb.w; \
    sm += msk[8]*xc.x;  sm += msk[9]*xc.y;  sm += msk[10]*xc.z; sm += msk[11]*xc.w; \
    sm += msk[12]*xd.x; sm += msk[13]*xd.y; sm += msk[14]*xd.z; sm += msk[15]*xd.w; \
    avx = sm / fcnt; }
    CELL(av0, tbase)  CELL(av1, tbase + 1)  CELL(av2, tbase + 2)
#undef CELL

    // ---- out(cc,o) = tanh(sum_t avg_t * Wcls[cc][t][o]) ----
    const float* __restrict__ wcl = Wcls + ((size_t)cc * T_IN + tbase) * T_OUT;
    float p[12];
    {
        const float4 wA0 = *(const float4*)&wcl[0];
        const float4 wA1 = *(const float4*)&wcl[4];
        const float4 wA2 = *(const float4*)&wcl[8];
        p[0] = av0 * wA0.x;  p[1] = av0 * wA0.y;  p[2]  = av0 * wA0.z;  p[3]  = av0 * wA0.w;
        p[4] = av0 * wA1.x;  p[5] = av0 * wA1.y;  p[6]  = av0 * wA1.z;  p[7]  = av0 * wA1.w;
        p[8] = av0 * wA2.x;  p[9] = av0 * wA2.y;  p[10] = av0 * wA2.z;  p[11] = av0 * wA2.w;
        const float4 wB0 = *(const float4*)&wcl[12];
        const float4 wB1 = *(const float4*)&wcl[16];
        const float4 wB2 = *(const float4*)&wcl[20];
        p[0] += av1 * wB0.x;  p[1] += av1 * wB0.y;  p[2]  += av1 * wB0.z;  p[3]  += av1 * wB0.w;
        p[4] += av1 * wB1.x;  p[5] += av1 * wB1.y;  p[6]  += av1 * wB1.z;  p[7]  += av1 * wB1.w;
        p[8] += av1 * wB2.x;  p[9] += av1 * wB2.y;  p[10] += av1 * wB2.z;  p[11] += av1 * wB2.w;
        const float4 wC0 = *(const float4*)&wcl[24];
        const float4 wC1 = *(const float4*)&wcl[28];
        const float4 wC2 = *(const float4*)&wcl[32];
        p[0] += av2 * wC0.x;  p[1] += av2 * wC0.y;  p[2]  += av2 * wC0.z;  p[3]  += av2 * wC0.w;
        p[4] += av2 * wC1.x;  p[5] += av2 * wC1.y;  p[6]  += av2 * wC1.z;  p[7]  += av2 * wC1.w;
        p[8] += av2 * wC2.x;  p[9] += av2 * wC2.y;  p[10] += av2 * wC2.z;  p[11] += av2 * wC2.w;
    }
    #pragma unroll
    for (int o = 0; o < 12; ++o) {
        p[o] += qperm<0xB1>(p[o]);   // + partner tq^1
        p[o] += qperm<0x4E>(p[o]);   // + pair tq^2  -> full sum over t
    }
    #pragma unroll
    for (int i = 0; i < 3; ++i) {
        const float va = (tq & 1) ? p[3 + i] : p[i];
        const float vb = (tq & 1) ? p[9 + i] : p[6 + i];
        const float v  = (tq & 2) ? vb : va;
        out[(size_t)node * (C * T_OUT) + cc * T_OUT + tbase + i] = tanhf(v);
    }
}

extern "C" void kernel_launch(void* const* d_in, const int* in_sizes, int n_in,
                              void* d_out, int out_size, void* d_ws, size_t ws_size,
                              hipStream_t stream) {
    const float* features  = (const float*)d_in[0];
    const float* input_seq = (const float*)d_in[1];
    const float* Wk        = (const float*)d_in[2];
    const float* bk        = (const float*)d_in[3];
    const float* Wq        = (const float*)d_in[4];
    const float* bq        = (const float*)d_in[5];
    const float* Wc        = (const float*)d_in[6];
    const float* bc        = (const float*)d_in[7];
    const float* Wcls      = (const float*)d_in[8];
    const int*   adj       = (const int*)d_in[9];
    float*       out       = (float*)d_out;

    embed_gcn_one<<<NNODE / 4, 256, 0, stream>>>(
        features, input_seq, Wk, bk, Wq, bq, Wc, bc, Wcls, adj, out);
}